// Round 6
// baseline (6353.332 us; speedup 1.0000x reference)
//
#include <hip/hip_runtime.h>
#include <stdint.h>

// ---------------- problem constants ----------------
#define TSTEPS 512
#define NB     256
#define DIN    85
#define DPAD   96
#define HID    512
#define ODIM   33
#define OPAD   48
#define TBROWS (TSTEPS*NB)
#define NBLK   256          // 16 strip-groups x 16 parts
#define SROWS  16           // batch rows per strip-group

typedef unsigned int u32;
typedef unsigned short u16;
typedef unsigned long long u64;
typedef __bf16 bf16x8 __attribute__((ext_vector_type(8)));
typedef float  f32x4  __attribute__((ext_vector_type(4)));

__device__ __forceinline__ u16 f2bf(float f) {
  u32 u = __float_as_uint(f);
  return (u16)((u + 0x7FFFu + ((u >> 16) & 1u)) >> 16);   // RNE
}
__device__ __forceinline__ float bf2f(u16 h) {
  return __uint_as_float(((u32)h) << 16);
}
__device__ __forceinline__ bf16x8 bc8(uint4 v) { return __builtin_bit_cast(bf16x8, v); }
__device__ __forceinline__ f32x4 mfma_bf16(bf16x8 a, bf16x8 b, f32x4 c) {
  return __builtin_amdgcn_mfma_f32_16x16x32_bf16(a, b, c, 0, 0, 0);
}
__device__ __forceinline__ float fsigmoid(float x) { return 1.0f / (1.0f + __expf(-x)); }
__device__ __forceinline__ float ftanh(float x)    { return 2.0f / (1.0f + __expf(-2.0f*x)) - 1.0f; }

// agent-scope (LLC-coherent) relaxed ops for cross-block mutable data
__device__ __forceinline__ void st_u32_llc(u32* p, u32 v) {
  __hip_atomic_store(p, v, __ATOMIC_RELAXED, __HIP_MEMORY_SCOPE_AGENT);
}
__device__ __forceinline__ u32 ld_u32_llc(const u32* p) {
  return __hip_atomic_load(p, __ATOMIC_RELAXED, __HIP_MEMORY_SCOPE_AGENT);
}
__device__ __forceinline__ u64 ld_u64_llc(const u64* p) {
  return __hip_atomic_load(p, __ATOMIC_RELAXED, __HIP_MEMORY_SCOPE_AGENT);
}

// generation tag: t>=1.  Starts at 1 (0xAA poison has LSB 0), alternates per plane.
__device__ __forceinline__ u32 gen_tag(int t) { return 1u ^ (((u32)(t - 1) >> 1) & 1u); }

// ---------------- prep: bf16 weight conversions ----------------
__global__ void __launch_bounds__(256) prep_kernel(
    const float* __restrict__ Whr, const float* __restrict__ Whz, const float* __restrict__ Whh,
    const float* __restrict__ Wxr, const float* __restrict__ Wxz, const float* __restrict__ Wxh,
    const float* __restrict__ Wro,
    u16* __restrict__ w_hb, u16* __restrict__ wx_hi, u16* __restrict__ wx_lo,
    u16* __restrict__ w_rob)
{
  int tid = blockIdx.x * blockDim.x + threadIdx.x;
  int np  = gridDim.x * blockDim.x;
  for (int i = tid; i < 3 * HID * HID; i += np) {
    int m = i / (HID * HID), r = i % (HID * HID);
    const float* src = (m == 0) ? Whr : ((m == 1) ? Whz : Whh);
    w_hb[i] = f2bf(src[r]);
  }
  for (int i = tid; i < 3 * HID * DPAD; i += np) {
    int m = i / (HID * DPAD), r = i % (HID * DPAD);
    int row = r / DPAD, k = r % DPAD;
    const float* src = (m == 0) ? Wxr : ((m == 1) ? Wxz : Wxh);
    u16 hi = 0, lo = 0;
    if (k < DIN) {
      float v = src[row * DIN + k];
      hi = f2bf(v);
      lo = f2bf(v - bf2f(hi));
    }
    wx_hi[i] = hi; wx_lo[i] = lo;
  }
  for (int i = tid; i < OPAD * HID; i += np) {
    int row = i / HID, k = i % HID;
    w_rob[i] = (row < ODIM) ? f2bf(Wro[row * HID + k]) : (u16)0;
  }
}

// ---------------- persistent recurrence kernel ----------------
#define LROW 520   // padded LDS row stride (u16)

__global__ void __launch_bounds__(256, 1) recur_kernel(
    const float* __restrict__ x,  const float* __restrict__ nr,
    const float* __restrict__ nz, const float* __restrict__ nh,
    const float* __restrict__ bhr, const float* __restrict__ bhz, const float* __restrict__ bhh,
    const u16* __restrict__ wx_hi, const u16* __restrict__ wx_lo, const u16* __restrict__ w_hb,
    u32* __restrict__ h_pk, u32* __restrict__ g_pk, u32* __restrict__ z_pk,
    u32* __restrict__ flags,
    u16* __restrict__ hs_out,
    const float* __restrict__ Wro, const float* __restrict__ bro, float* __restrict__ out,
    int do_c)
{
  // union strip buffer: A = split h (hi,lo); B = split g (hi,lo); C = f32 scratch
  __shared__ __attribute__((aligned(16))) u16 sBig[2 * SROWS * LROW];   // 33280 B
  __shared__ __attribute__((aligned(16))) u16 sXAh[SROWS][104];
  __shared__ __attribute__((aligned(16))) u16 sXAl[SROWS][104];
  __shared__ __attribute__((aligned(16))) u16 sXBh[SROWS][104];
  __shared__ __attribute__((aligned(16))) u16 sXBl[SROWS][104];
  __shared__ __attribute__((aligned(16))) float sC[2][64][4];

  u16 (*sHh)[LROW] = (u16(*)[LROW])sBig;
  u16 (*sHl)[LROW] = (u16(*)[LROW])(sBig + SROWS * LROW);
  u16 (*sGh)[LROW] = sHh;
  u16 (*sGl)[LROW] = sHl;
  float* sC2 = (float*)sBig;

  const int bid  = blockIdx.x;
  const int tid  = threadIdx.x;
  const int lane = tid & 63;
  const int wave = tid >> 6;
  const int strip = bid & 15;     // group id (16 batch rows); members share bid%8 (XCD heuristic)
  const int part  = bid >> 4;     // member 0..15

  u32* gprog = flags + strip * 16;   // one 64B line per group: per-member progress

  // ---- phase A geometry: [16 rows x 64 cols] over [256 x 1024] (R cols | Z cols) ----
  const int isZ = part >= 8;
  const int ncA = (part & 7) * 64;
  const u16*  WA   = w_hb  + (size_t)(isZ ? 1 : 0) * HID * HID;
  const u16*  WXAh = wx_hi + (size_t)(isZ ? 1 : 0) * HID * DPAD;
  const u16*  WXAl = wx_lo + (size_t)(isZ ? 1 : 0) * HID * DPAD;
  const float* nA  = isZ ? nz : nr;
  const int rowl  = lane & 15;
  const int colA  = ncA + wave * 16 + rowl;
  const float biasA = (isZ ? bhz : bhr)[colA];

  // ---- phase B geometry: [16 rows x 32 cols]; waves: n-tile x k-half ----
  const int ncB  = part * 32;
  const u16*  WH   = w_hb  + (size_t)2 * HID * HID;
  const u16*  WXBh = wx_hi + (size_t)2 * HID * DPAD;
  const u16*  WXBl = wx_lo + (size_t)2 * HID * DPAD;
  const int ntB = wave & 1;
  const int khB = wave >> 1;
  const int colB = ncB + ntB * 16 + rowl;
  const float biasB = bhh[colB];

  float h_old[4] = {0.f, 0.f, 0.f, 0.f};

  // zero x-buffer k-pads once
  for (int c = tid; c < SROWS * (104 - DIN); c += 256) {
    int row = c / (104 - DIN), k = DIN + c % (104 - DIN);
    sXAh[row][k] = 0; sXAl[row][k] = 0; sXBh[row][k] = 0; sXBl[row][k] = 0;
  }
  // stage xA for t=1
  {
    const size_t xoff = (size_t)(strip * SROWS) * DIN;
    for (int c = tid; c < SROWS * DIN; c += 256) {
      int row = c / DIN, k = c - row * DIN;
      float v = x[xoff + c] + nA[xoff + c];
      u16 hi = f2bf(v);
      sXAh[row][k] = hi;
      sXAl[row][k] = f2bf(v - bf2f(hi));
    }
  }

  for (int t = 1; t <= TSTEPS; ++t) {
    const u32 tg = gen_tag(t);                               // tag for everything written this step
    const u32 hexp = (t == 1) ? 0u : gen_tag(t - 1);         // expected tag on h(t-1)

    // ---------- phase C (small-ws inline out-projection): out(t-2) from h(t-1) ----------
    if (do_c && t >= 2) {
      const int row = strip * SROWS + part;
      const int o = tid >> 3, q = tid & 7;
      const u32* hp = h_pk + (size_t)((t - 1) & 1) * NB * HID + (size_t)row * HID + q * 64;
      float a = 0.f;
      #pragma unroll
      for (int c8 = 0; c8 < 8; ++c8) {
        u32 vv[8];
        #pragma unroll
        for (int j = 0; j < 8; ++j) vv[j] = ld_u32_llc(&hp[c8 * 8 + j]);
        for (;;) {
          bool ok = true;
          #pragma unroll
          for (int j = 0; j < 8; ++j) ok = ok && ((vv[j] & 1u) == hexp);
          if (__all(ok)) break;
          #pragma unroll
          for (int j = 0; j < 8; ++j) vv[j] = ld_u32_llc(&hp[c8 * 8 + j]);
        }
        #pragma unroll
        for (int j = 0; j < 8; ++j) {
          float hv = bf2f((u16)(vv[j] >> 16)) + bf2f((u16)(vv[j] & 0xFFFEu));
          a += hv * Wro[(size_t)o * HID + q * 64 + c8 * 8 + j];
        }
      }
      __syncthreads();
      sC2[o * 8 + q] = a;
      if (tid < 8) {
        const u32* hp2 = h_pk + (size_t)((t - 1) & 1) * NB * HID + (size_t)row * HID + tid * 64;
        float a2 = 0.f;
        #pragma unroll
        for (int c8 = 0; c8 < 8; ++c8) {
          u32 vv[8];
          #pragma unroll
          for (int j = 0; j < 8; ++j) vv[j] = ld_u32_llc(&hp2[c8 * 8 + j]);
          // tags already verified above for this row by the full block pass
          #pragma unroll
          for (int j = 0; j < 8; ++j) {
            float hv = bf2f((u16)(vv[j] >> 16)) + bf2f((u16)(vv[j] & 0xFFFEu));
            a2 += hv * Wro[(size_t)32 * HID + tid * 64 + c8 * 8 + j];
          }
        }
        sC2[32 * 8 + tid] = a2;
      }
      __syncthreads();
      if (tid < ODIM) {
        float s = bro[tid];
        #pragma unroll
        for (int q2 = 0; q2 < 8; ++q2) s += sC2[tid * 8 + q2];
        out[(size_t)((t - 2) * NB + row) * ODIM + tid] = s;
      }
      __syncthreads();
    }

    // ================= PHASE A: R and Z =================
    // issue h(t-1) strip staging loads (16 u64/thread; u64 = 2 tagged cols)
    const u64* hsrc = (const u64*)(h_pk + (size_t)((t - 1) & 1) * NB * HID);
    u64 hreg[SROWS];
    #pragma unroll
    for (int i = 0; i < SROWS; ++i)
      hreg[i] = ld_u64_llc(&hsrc[(size_t)(strip * SROWS + i) * 256 + tid]);

    // overlapped write-safety poll: g(t)/z(t) overwrite gen t-2 -> need all prog >= t-2
    if (wave == 0 && t > 2) {
      const u32 target = (u32)(t - 2);
      for (;;) {
        u32 a = (lane < 16) ? ld_u32_llc(&gprog[lane]) : target;
        if (__all(a >= target)) break;
      }
    }

    // verify h tags (retry all on any miss)
    for (;;) {
      bool ok = true;
      #pragma unroll
      for (int i = 0; i < SROWS; ++i)
        ok = ok && (((u32)hreg[i] & 1u) == hexp) && (((u32)(hreg[i] >> 32) & 1u) == hexp);
      if (__all(ok)) break;
      #pragma unroll
      for (int i = 0; i < SROWS; ++i)
        hreg[i] = ld_u64_llc(&hsrc[(size_t)(strip * SROWS + i) * 256 + tid]);
    }
    // split into LDS planes (mask tag bits out of lo)
    #pragma unroll
    for (int i = 0; i < SROWS; ++i) {
      u32 v0 = (u32)hreg[i], v1 = (u32)(hreg[i] >> 32);
      *(u32*)&sHh[i][tid * 2] = (v0 >> 16) | (v1 & 0xFFFF0000u);
      *(u32*)&sHl[i][tid * 2] = (v0 & 0xFFFEu) | ((v1 & 0xFFFEu) << 16);
    }
    __syncthreads();

    f32x4 accA = {0.f, 0.f, 0.f, 0.f};
    // x-projection (K=96; split x, split Wx)
    #pragma unroll
    for (int ks = 0; ks < 3; ++ks) {
      int kk = ks * 32 + 8 * (lane >> 4);
      bf16x8 wh = bc8(*(const uint4*)&WXAh[(size_t)colA * DPAD + kk]);
      bf16x8 wl = bc8(*(const uint4*)&WXAl[(size_t)colA * DPAD + kk]);
      bf16x8 xh = bc8(*(const uint4*)&sXAh[rowl][kk]);
      bf16x8 xl = bc8(*(const uint4*)&sXAl[rowl][kk]);
      accA = mfma_bf16(xh, wh, accA);
      accA = mfma_bf16(xl, wh, accA);
      accA = mfma_bf16(xh, wl, accA);
    }
    // h GEMM (K=512, split h)
    #pragma unroll
    for (int kk16 = 0; kk16 < 16; ++kk16) {
      int k = kk16 * 32 + 8 * (lane >> 4);
      bf16x8 bw = bc8(*(const uint4*)&WA[(size_t)colA * HID + k]);
      bf16x8 ah = bc8(*(const uint4*)&sHh[rowl][k]);
      bf16x8 al = bc8(*(const uint4*)&sHl[rowl][k]);
      accA = mfma_bf16(ah, bw, accA);
      accA = mfma_bf16(al, bw, accA);
    }

    // epilogue A: tagged g / z stores (write-safety guaranteed by the poll above)
    {
      u32* gdst = g_pk + (size_t)(t & 1) * NB * HID;
      u32* zdst = z_pk + (size_t)(t & 1) * NB * HID;
      #pragma unroll
      for (int r = 0; r < 4; ++r) {
        int rowm = (lane >> 4) * 4 + r;
        int grow = strip * SROWS + rowm;
        float val = fsigmoid(accA[r] + biasA);
        size_t idx = (size_t)grow * HID + colA;
        if (!isZ) {
          float hcur = bf2f(sHh[rowm][colA]) + bf2f(sHl[rowm][colA]);
          float g = val * hcur;
          u16 gh = f2bf(g);
          u16 gl = f2bf(g - bf2f(gh));
          st_u32_llc(&gdst[idx], ((u32)gh << 16) | ((u32)gl & 0xFFFEu) | tg);
        } else {
          st_u32_llc(&zdst[idx], (__float_as_uint(val) & ~1u) | tg);
        }
      }
    }

    // ================= PHASE B: Hh + state update =================
    // issue g(t) staging loads
    const u64* gsrc = (const u64*)(g_pk + (size_t)(t & 1) * NB * HID);
    u64 greg[SROWS];
    #pragma unroll
    for (int i = 0; i < SROWS; ++i)
      greg[i] = ld_u64_llc(&gsrc[(size_t)(strip * SROWS + i) * 256 + tid]);

    // issue z(t) loads (khB==0 waves)
    u32 zr[4];
    if (khB == 0) {
      const u32* zsrc = z_pk + (size_t)(t & 1) * NB * HID;
      #pragma unroll
      for (int r = 0; r < 4; ++r) {
        int brow = strip * SROWS + (lane >> 4) * 4 + r;
        zr[r] = ld_u32_llc(&zsrc[(size_t)brow * HID + colB]);
      }
    }

    // stage xB(t) while loads are in flight
    {
      const size_t xoff = (size_t)((t - 1) * NB + strip * SROWS) * DIN;
      for (int c = tid; c < SROWS * DIN; c += 256) {
        int row = c / DIN, k = c - row * DIN;
        float v = x[xoff + c] + nh[xoff + c];
        u16 hi = f2bf(v);
        sXBh[row][k] = hi;
        sXBl[row][k] = f2bf(v - bf2f(hi));
      }
    }

    // overlapped write-safety poll: h(t) overwrites gen t-2 -> need all prog >= t-1
    if (wave == 0 && t > 1) {
      const u32 target = (u32)(t - 1);
      for (;;) {
        u32 a = (lane < 16) ? ld_u32_llc(&gprog[lane]) : target;
        if (__all(a >= target)) break;
      }
    }

    // verify z tags
    if (khB == 0) {
      const u32* zsrc = z_pk + (size_t)(t & 1) * NB * HID;
      for (;;) {
        bool ok = true;
        #pragma unroll
        for (int r = 0; r < 4; ++r) ok = ok && ((zr[r] & 1u) == tg);
        if (__all(ok)) break;
        #pragma unroll
        for (int r = 0; r < 4; ++r) {
          int brow = strip * SROWS + (lane >> 4) * 4 + r;
          zr[r] = ld_u32_llc(&zsrc[(size_t)brow * HID + colB]);
        }
      }
    }
    // verify g tags
    for (;;) {
      bool ok = true;
      #pragma unroll
      for (int i = 0; i < SROWS; ++i)
        ok = ok && (((u32)greg[i] & 1u) == tg) && (((u32)(greg[i] >> 32) & 1u) == tg);
      if (__all(ok)) break;
      #pragma unroll
      for (int i = 0; i < SROWS; ++i)
        greg[i] = ld_u64_llc(&gsrc[(size_t)(strip * SROWS + i) * 256 + tid]);
    }
    #pragma unroll
    for (int i = 0; i < SROWS; ++i) {
      u32 v0 = (u32)greg[i], v1 = (u32)(greg[i] >> 32);
      *(u32*)&sGh[i][tid * 2] = (v0 >> 16) | (v1 & 0xFFFF0000u);
      *(u32*)&sGl[i][tid * 2] = (v0 & 0xFFFEu) | ((v1 & 0xFFFEu) << 16);
    }
    __syncthreads();

    // progress: this block finished ALL gen-t exchange reads (h read earlier, z/g just verified)
    if (tid == 0) st_u32_llc(&gprog[part], (u32)t);

    f32x4 accB = {0.f, 0.f, 0.f, 0.f};
    if (khB == 0) {
      #pragma unroll
      for (int ks = 0; ks < 3; ++ks) {
        int kk = ks * 32 + 8 * (lane >> 4);
        bf16x8 wh = bc8(*(const uint4*)&WXBh[(size_t)colB * DPAD + kk]);
        bf16x8 wl = bc8(*(const uint4*)&WXBl[(size_t)colB * DPAD + kk]);
        bf16x8 xh = bc8(*(const uint4*)&sXBh[rowl][kk]);
        bf16x8 xl = bc8(*(const uint4*)&sXBl[rowl][kk]);
        accB = mfma_bf16(xh, wh, accB);
        accB = mfma_bf16(xl, wh, accB);
        accB = mfma_bf16(xh, wl, accB);
      }
    }
    #pragma unroll
    for (int f = 0; f < 8; ++f) {
      int k = khB * 256 + f * 32 + 8 * (lane >> 4);
      bf16x8 bw = bc8(*(const uint4*)&WH[(size_t)colB * HID + k]);
      bf16x8 gh = bc8(*(const uint4*)&sGh[rowl][k]);
      bf16x8 gl = bc8(*(const uint4*)&sGl[rowl][k]);
      accB = mfma_bf16(gh, bw, accB);
      accB = mfma_bf16(gl, bw, accB);
    }
    if (khB == 1) *(f32x4*)&sC[ntB][lane][0] = accB;
    __syncthreads();

    if (khB == 0) {
      f32x4 oth = *(const f32x4*)&sC[ntB][lane][0];
      accB[0] += oth[0]; accB[1] += oth[1]; accB[2] += oth[2]; accB[3] += oth[3];
      u32* hdst = h_pk + (size_t)(t & 1) * NB * HID;
      #pragma unroll
      for (int r = 0; r < 4; ++r) {
        int brow = strip * SROWS + (lane >> 4) * 4 + r;
        float z = __uint_as_float(zr[r] & ~1u);
        float hh = ftanh(accB[r] + biasB);
        float hn = z * h_old[r] + (1.0f - z) * hh;
        h_old[r] = hn;
        u16 hi = f2bf(hn);
        u16 lo = f2bf(hn - bf2f(hi));
        st_u32_llc(&hdst[(size_t)brow * HID + colB], ((u32)hi << 16) | ((u32)lo & 0xFFFEu) | tg);
        if (hs_out)
          hs_out[(size_t)((t - 1) * NB + brow) * HID + colB] = hi;
      }
    }

    // stage xA(t+1) (overlaps next step's h retry)
    if (t < TSTEPS) {
      const size_t xoff = (size_t)(t * NB + strip * SROWS) * DIN;
      for (int c = tid; c < SROWS * DIN; c += 256) {
        int row = c / DIN, k = c - row * DIN;
        float v = x[xoff + c] + nA[xoff + c];
        u16 hi = f2bf(v);
        sXAh[row][k] = hi;
        sXAl[row][k] = f2bf(v - bf2f(hi));
      }
    }
  }

  // final phase C (small-ws): out(TSTEPS-1) from h(TSTEPS)
  if (do_c) {
    const int t = TSTEPS + 1;                 // virtual step for tag math
    const u32 hexp = gen_tag(t - 1);
    const int row = strip * SROWS + part;
    const int o = tid >> 3, q = tid & 7;
    const u32* hp = h_pk + (size_t)((t - 1) & 1) * NB * HID + (size_t)row * HID + q * 64;
    float a = 0.f;
    #pragma unroll
    for (int c8 = 0; c8 < 8; ++c8) {
      u32 vv[8];
      #pragma unroll
      for (int j = 0; j < 8; ++j) vv[j] = ld_u32_llc(&hp[c8 * 8 + j]);
      for (;;) {
        bool ok = true;
        #pragma unroll
        for (int j = 0; j < 8; ++j) ok = ok && ((vv[j] & 1u) == hexp);
        if (__all(ok)) break;
        #pragma unroll
        for (int j = 0; j < 8; ++j) vv[j] = ld_u32_llc(&hp[c8 * 8 + j]);
      }
      #pragma unroll
      for (int j = 0; j < 8; ++j) {
        float hv = bf2f((u16)(vv[j] >> 16)) + bf2f((u16)(vv[j] & 0xFFFEu));
        a += hv * Wro[(size_t)o * HID + q * 64 + c8 * 8 + j];
      }
    }
    __syncthreads();
    sC2[o * 8 + q] = a;
    if (tid < 8) {
      const u32* hp2 = h_pk + (size_t)((t - 1) & 1) * NB * HID + (size_t)row * HID + tid * 64;
      float a2 = 0.f;
      #pragma unroll
      for (int c8 = 0; c8 < 8; ++c8) {
        u32 vv[8];
        #pragma unroll
        for (int j = 0; j < 8; ++j) vv[j] = ld_u32_llc(&hp2[c8 * 8 + j]);
        #pragma unroll
        for (int j = 0; j < 8; ++j) {
          float hv = bf2f((u16)(vv[j] >> 16)) + bf2f((u16)(vv[j] & 0xFFFEu));
          a2 += hv * Wro[(size_t)32 * HID + tid * 64 + c8 * 8 + j];
        }
      }
      sC2[32 * 8 + tid] = a2;
    }
    __syncthreads();
    if (tid < ODIM) {
      float s = bro[tid];
      #pragma unroll
      for (int q2 = 0; q2 < 8; ++q2) s += sC2[tid * 8 + q2];
      out[(size_t)((TSTEPS - 1) * NB + row) * ODIM + tid] = s;
    }
  }
}

// ---------------- output projection (big-ws path) ----------------
__global__ void __launch_bounds__(256) out_kernel(
    const u16* __restrict__ hs_out,
    const u16* __restrict__ w_rob, const float* __restrict__ b_ro,
    float* __restrict__ out)
{
  __shared__ __attribute__((aligned(16))) u16 sOh[128][72];

  const int m0   = blockIdx.x * 128;
  const int tid  = threadIdx.x;
  const int lane = tid & 63, wave = tid >> 6;

  f32x4 acc[2][3];
  for (int a = 0; a < 2; ++a) for (int b = 0; b < 3; ++b) acc[a][b] = {0.f, 0.f, 0.f, 0.f};

  for (int kc = 0; kc < 8; ++kc) {
    __syncthreads();
    #pragma unroll
    for (int i = 0; i < 4; ++i) {
      int c = tid + 256 * i; int row = c >> 3, seg = c & 7;
      *(uint4*)&sOh[row][seg * 8] =
        *(const uint4*)&hs_out[(size_t)(m0 + row) * HID + kc * 64 + seg * 8];
    }
    __syncthreads();
    #pragma unroll
    for (int ks = 0; ks < 2; ++ks) {
      int klocal = ks * 32 + 8 * (lane >> 4);
      int kglob  = kc * 64 + klocal;
      bf16x8 ah[2];
      #pragma unroll
      for (int mf = 0; mf < 2; ++mf) {
        int rowl = wave * 32 + mf * 16 + (lane & 15);
        ah[mf] = bc8(*(const uint4*)&sOh[rowl][klocal]);
      }
      #pragma unroll
      for (int nf = 0; nf < 3; ++nf) {
        int wrow = nf * 16 + (lane & 15);
        bf16x8 bw = bc8(*(const uint4*)&w_rob[(size_t)wrow * HID + kglob]);
        #pragma unroll
        for (int mf = 0; mf < 2; ++mf)
          acc[mf][nf] = mfma_bf16(ah[mf], bw, acc[mf][nf]);
      }
    }
  }
  for (int nf = 0; nf < 3; ++nf) {
    int o = nf * 16 + (lane & 15);
    if (o < ODIM) {
      float bb = b_ro[o];
      for (int mf = 0; mf < 2; ++mf)
        for (int r = 0; r < 4; ++r) {
          int R = m0 + wave * 32 + mf * 16 + (lane >> 4) * 4 + r;
          out[(size_t)R * ODIM + o] = acc[mf][nf][r] + bb;
        }
    }
  }
}

// ---------------- launcher ----------------
extern "C" void kernel_launch(void* const* d_in, const int* in_sizes, int n_in,
                              void* d_out, int out_size, void* d_ws, size_t ws_size,
                              hipStream_t stream)
{
  const float* x   = (const float*)d_in[0];
  const float* nr  = (const float*)d_in[1];
  const float* nz  = (const float*)d_in[2];
  const float* nh  = (const float*)d_in[3];
  const float* Wxr = (const float*)d_in[4];
  const float* Wxz = (const float*)d_in[5];
  const float* Wxh = (const float*)d_in[6];
  const float* Whr = (const float*)d_in[7];
  const float* bhr = (const float*)d_in[8];
  const float* Whz = (const float*)d_in[9];
  const float* bhz = (const float*)d_in[10];
  const float* Whh = (const float*)d_in[11];
  const float* bhh = (const float*)d_in[12];
  const float* Wro = (const float*)d_in[13];
  const float* bro = (const float*)d_in[14];
  float* out = (float*)d_out;

  char* ws = (char*)d_ws;
  size_t off = 0;
  auto alloc = [&](size_t bytes) -> char* {
    char* p = ws + off;
    off += (bytes + 255) & ~(size_t)255;
    return p;
  };
  u32*  h_pk  = (u32*) alloc((size_t)2 * NB * HID * 4);   // tagged, double-buffered
  u32*  g_pk  = (u32*) alloc((size_t)2 * NB * HID * 4);
  u32*  z_pk  = (u32*) alloc((size_t)2 * NB * HID * 4);
  u16*  w_hb  = (u16*) alloc((size_t)3 * HID * HID * 2);
  u16*  wx_hi = (u16*) alloc((size_t)3 * HID * DPAD * 2);
  u16*  wx_lo = (u16*) alloc((size_t)3 * HID * DPAD * 2);
  u16*  w_rob = (u16*) alloc((size_t)OPAD * HID * 2);
  u32*  flags = (u32*) alloc((size_t)16 * 16 * 4);        // 16 groups x 16 members progress
  size_t small_need = off;
  if (ws_size < small_need) return;   // fail numerically, never scribble

  u16* hs_out = (u16*)(ws + off);
  size_t big_need = off + (size_t)TBROWS * HID * 2 + 256;
  bool big = (ws_size >= big_need);
  if (!big) hs_out = nullptr;

  hipMemsetAsync(flags, 0, (size_t)16 * 16 * 4, stream);
  hipMemsetAsync(h_pk,  0, (size_t)NB * HID * 4, stream);   // h(0) plane: tag 0, value 0

  prep_kernel<<<512, 256, 0, stream>>>(Whr, Whz, Whh, Wxr, Wxz, Wxh, Wro,
                                       w_hb, wx_hi, wx_lo, w_rob);

  recur_kernel<<<NBLK, 256, 0, stream>>>(
      x, nr, nz, nh, bhr, bhz, bhh, wx_hi, wx_lo, w_hb,
      h_pk, g_pk, z_pk, flags, hs_out, Wro, bro, out, big ? 0 : 1);

  if (big)
    out_kernel<<<TBROWS / 128, 256, 0, stream>>>(hs_out, w_rob, bro, out);
}